// Round 8
// baseline (1786.519 us; speedup 1.0000x reference)
//
#include <hip/hip_runtime.h>
#include <math.h>

#define NROWS 131072
#define NSEG  64
#define HH    512
#define BM    256
#define BN    256
#define BK    32
#define NT    (HH / BK)   // 16 K-steps

typedef unsigned short u16;
typedef unsigned int   u32;
typedef __attribute__((ext_vector_type(8))) short short8;
typedef __attribute__((ext_vector_type(4))) float f32x4;
typedef __attribute__((ext_vector_type(4))) u32   u32x4;

__device__ __forceinline__ u32 f2u(float f){ union {float f; u32 u;} c; c.f=f; return c.u; }
__device__ __forceinline__ float u2f(u32 u){ union {u32 u; float f;} c; c.u=u; return c.f; }
__device__ __forceinline__ u16 bf16_rne(float f){
  u32 u = f2u(f);
  u32 r = u + 0x7FFFu + ((u >> 16) & 1u);
  return (u16)(r >> 16);
}
__device__ __forceinline__ float fast_tanh(float x){
  float e = __expf(2.0f * x);
  return 1.0f - __fdividef(2.0f, e + 1.0f);
}

// ---------------- prep: fused w2split (blocks 0..1023) + hproj (blocks 1024..1279)
__global__ __launch_bounds__(256)
void prep_kernel(const float* __restrict__ hidden, const float* __restrict__ W,
                 float* __restrict__ hproj, u16* __restrict__ w2hi, u16* __restrict__ w2lo)
{
  const int bid = blockIdx.x;
  if (bid < 1024) {
    // split W2 = W[:, 512:1024] into bf16 hi/lo, row-major [j][k]
    const int idx = bid * 256 + threadIdx.x;   // j*512 + k
    const int j = idx >> 9, k = idx & 511;
    const float x = W[(size_t)j * 1024 + 512 + k];
    const u32 u = f2u(x);
    w2hi[idx] = (u16)(u >> 16);
    w2lo[idx] = bf16_rne(x - u2f(u & 0xFFFF0000u));
  } else {
    // hproj[b][j] = sum_k hidden[b][k] * W[j][k]
    const int b    = (bid - 1024) >> 2;        // segment
    const int q    = (bid - 1024) & 3;         // j-quarter
    const int tid  = threadIdx.x;
    const int wave = tid >> 6;
    const int lane = tid & 63;
    const float* hrow = hidden + (size_t)b * HH + lane * 8;
    const float4 h0 = *(const float4*)(hrow);
    const float4 h1 = *(const float4*)(hrow + 4);
    for (int j = q * 128 + wave; j < q * 128 + 128; j += 4) {
      const float* wrow = W + (size_t)j * 1024 + lane * 8;
      const float4 w0 = *(const float4*)(wrow);
      const float4 w1 = *(const float4*)(wrow + 4);
      float acc = h0.x*w0.x + h0.y*w0.y + h0.z*w0.z + h0.w*w0.w
                + h1.x*w1.x + h1.y*w1.y + h1.z*w1.z + h1.w*w1.w;
      #pragma unroll
      for (int o = 32; o; o >>= 1) acc += __shfl_xor(acc, o);
      if (lane == 0) hproj[(size_t)b * HH + j] = acc;
    }
  }
}

// ---------------- fused GEMM v7: NO LDS STAGING, NO K-LOOP BARRIERS.
// B (1 MB) is L2-resident; A has only 2-way reuse (col-pair) -> L1/L2 catches
// it. MFMA fragments load DIRECTLY global->register: A as 2x f32x4 per row-frag
// (64 lanes = 16 rows x 128 B contiguous), B as short8 per col-frag (64 B
// segments, L2-hot). LDS = 2 KB epilogue scratch only -> 2 blocks/CU,
// 4 free-running waves/SIMD: latency hiding by TLP, MFMA pipe is the only
// shared serial resource (384 MFMA x 19.4 cyc = 7450 cyc/SIMD/K-step vs
// ~800 cyc VALU split on the separate VALU pipe). __launch_bounds__(512,4)
// caps VGPR at 128 to guarantee the occupancy. XCD mapping: a row-tile's
// col-pair lands on the same XCD 8 dispatches apart (A re-read = L2 hit).
// A split hi/lo in-register (v_perm); B pre-split. 3-product split-bf16 MFMA,
// fused tanh+dot-v epilogue, race-free LDS cross-wave reduction.
__global__ __launch_bounds__(512, 4)
void gemm_fused_kernel(const float* __restrict__ enc,
                       const u16* __restrict__ w2hi, const u16* __restrict__ w2lo,
                       const float* __restrict__ hproj, const float* __restrict__ vvec,
                       const int* __restrict__ seg,
                       float* __restrict__ scores0, float* __restrict__ scores1)
{
  __shared__ float spart[8][64];      // 2 KB: per-wave per-row partials

  const int tid = threadIdx.x;
  const int b   = blockIdx.x;
  // XCD-pairing: row-tile = (b>>4)*8 + (b&7), col-half = (b>>3)&1.
  // The two blocks sharing a row-tile have dispatch ids 8 apart -> same XCD
  // (hw round-robins blockIdx%8), temporally adjacent -> A re-read hits L2.
  const int row0 = (((b >> 4) << 3) | (b & 7)) * BM;
  const int col0 = ((b >> 3) & 1) * BN;

  const int wave = tid >> 6;
  const int lane = tid & 63;
  const int wrow = (wave >> 1) * 64;    // 4 row-waves
  const int wcol = (wave & 1) * 128;    // 2 col-waves
  const int l15  = lane & 15;
  const int quad = lane >> 4;

  // per-lane element offsets (32-bit; addresses computed by compiler)
  int aoff[4];
  #pragma unroll
  for (int i = 0; i < 4; i++)
    aoff[i] = (row0 + wrow + i * 16 + l15) * HH + quad * 8;
  int boff[8];
  #pragma unroll
  for (int j = 0; j < 8; j++)
    boff[j] = (col0 + wcol + j * 16 + l15) * HH + quad * 8;

  f32x4 acc[4][8];
  #pragma unroll
  for (int i = 0; i < 4; i++)
    #pragma unroll
    for (int j = 0; j < 8; j++)
      acc[i][j] = (f32x4){0.f, 0.f, 0.f, 0.f};

  // ---- prefetch A(t=0) raw fp32 into registers ----
  f32x4 a0[4], a1[4];
  #pragma unroll
  for (int i = 0; i < 4; i++) {
    a0[i] = *(const f32x4*)(enc + aoff[i]);
    a1[i] = *(const f32x4*)(enc + aoff[i] + 4);
  }

  #pragma unroll 1
  for (int t = 0; t < NT; ++t) {
    // ---- split current A into hi/lo bf16 fragments (VALU, v_perm) ----
    short8 ah[4], al[4];
    #pragma unroll
    for (int i = 0; i < 4; i++) {
      union { u32x4 w; short8 s; } Hh, Ll;
      #pragma unroll
      for (int p = 0; p < 4; p++) {
        const float xa = (p < 2) ? a0[i][2 * p] : a1[i][2 * p - 4];
        const float xb = (p < 2) ? a0[i][2 * p + 1] : a1[i][2 * p - 3];
        const u32 ua = f2u(xa), ub = f2u(xb);
        Hh.w[p] = __builtin_amdgcn_perm(ub, ua, 0x07060302u);   // [ub_hi16 | ua_hi16]
        const float ra = xa - u2f(ua & 0xFFFF0000u);
        const float rb = xb - u2f(ub & 0xFFFF0000u);
        Ll.w[p] = __builtin_amdgcn_perm(f2u(rb), f2u(ra), 0x07060302u);
      }
      ah[i] = Hh.s;
      al[i] = Ll.s;
    }

    // ---- prefetch A(t+1): retires during the ~7000-cyc MFMA block below ----
    if (t + 1 < NT) {
      #pragma unroll
      for (int i = 0; i < 4; i++) {
        a0[i] = *(const f32x4*)(enc + aoff[i] + (t + 1) * BK);
        a1[i] = *(const f32x4*)(enc + aoff[i] + (t + 1) * BK + 4);
      }
    }

    // ---- B streamed per col-frag (L2-hot), prefetch one j ahead ----
    short8 bh = *(const short8*)(w2hi + boff[0] + t * BK);
    short8 bl = *(const short8*)(w2lo + boff[0] + t * BK);
    #pragma unroll
    for (int j = 0; j < 8; j++) {
      short8 bhn, bln;
      if (j < 7) {
        bhn = *(const short8*)(w2hi + boff[j + 1] + t * BK);
        bln = *(const short8*)(w2lo + boff[j + 1] + t * BK);
      }
      __builtin_amdgcn_s_setprio(1);
      #pragma unroll
      for (int i = 0; i < 4; i++) {
        acc[i][j] = __builtin_amdgcn_mfma_f32_16x16x32_bf16(ah[i], bh, acc[i][j], 0, 0, 0);
        acc[i][j] = __builtin_amdgcn_mfma_f32_16x16x32_bf16(al[i], bh, acc[i][j], 0, 0, 0);
        acc[i][j] = __builtin_amdgcn_mfma_f32_16x16x32_bf16(ah[i], bl, acc[i][j], 0, 0, 0);
      }
      __builtin_amdgcn_s_setprio(0);
      bh = bhn;
      bl = bln;
    }
  }

  // ---- epilogue: + hproj, tanh, dot v, reduce over the wave's 128 cols,
  // deposit per-row partial in LDS, cross-wave sum of the two col-halves,
  // one coalesced store per row. ----
  int   jn[8];
  float vv[8];
  #pragma unroll
  for (int j = 0; j < 8; j++) { jn[j] = col0 + wcol + j * 16 + l15; vv[j] = vvec[jn[j]]; }

  #pragma unroll
  for (int i = 0; i < 4; i++) {
    #pragma unroll
    for (int r = 0; r < 4; r++) {
      const int lr = wrow + i * 16 + quad * 4 + r;           // local row 0..255
      const float* hp = hproj + (size_t)seg[row0 + lr] * HH;
      float p = 0.f;
      #pragma unroll
      for (int j = 0; j < 8; j++) {
        const float c = acc[i][j][r] + hp[jn[j]];
        p += fast_tanh(c) * vv[j];
      }
      p += __shfl_xor(p, 1);
      p += __shfl_xor(p, 2);
      p += __shfl_xor(p, 4);
      p += __shfl_xor(p, 8);
      if (l15 == 0) spart[wave][i * 16 + quad * 4 + r] = p;  // wave's 64-row slab
    }
  }
  __syncthreads();

  // waves 2k (cols 0..127) and 2k+1 (cols 128..255) cover the same rows:
  // sum the pair, one writer per row of this block's col-half buffer.
  float* __restrict__ sbuf = (col0 == 0) ? scores0 : scores1;
  if (tid < 256) {
    const int rw = tid >> 6;          // row-wave 0..3
    const int rr = tid & 63;
    sbuf[row0 + tid] = spart[rw * 2][rr] + spart[rw * 2 + 1][rr];
  }
}

// ---------------- segment softmax: one block per segment (ids sorted);
// scores = scores0 + scores1 (two col-half partials)
__global__ __launch_bounds__(256)
void seg_softmax_kernel(const float* __restrict__ scores0, const float* __restrict__ scores1,
                        const int* __restrict__ seg, float* __restrict__ out)
{
  const int b    = blockIdx.x;
  const int tid  = threadIdx.x;
  const int wv   = tid >> 6;
  const int lane = tid & 63;
  __shared__ float red[4];

  int lo = 0, hi = NROWS;
  while (lo < hi) { int mid = (lo + hi) >> 1; if (seg[mid] < b) lo = mid + 1; else hi = mid; }
  const int start = lo;
  lo = 0; hi = NROWS;
  while (lo < hi) { int mid = (lo + hi) >> 1; if (seg[mid] < b + 1) lo = mid + 1; else hi = mid; }
  const int end = lo;

  float lm = -3.4e38f;
  for (int i = start + tid; i < end; i += 256) lm = fmaxf(lm, scores0[i] + scores1[i]);
  #pragma unroll
  for (int o = 32; o; o >>= 1) lm = fmaxf(lm, __shfl_xor(lm, o));
  if (lane == 0) red[wv] = lm;
  __syncthreads();
  const float gm = fmaxf(fmaxf(red[0], red[1]), fmaxf(red[2], red[3]));
  __syncthreads();

  float ls = 0.f;
  for (int i = start + tid; i < end; i += 256) ls += expf(scores0[i] + scores1[i] - gm);
  #pragma unroll
  for (int o = 32; o; o >>= 1) ls += __shfl_xor(ls, o);
  if (lane == 0) red[wv] = ls;
  __syncthreads();
  const float denom = red[0] + red[1] + red[2] + red[3];
  const float inv = 1.0f / denom;

  for (int i = start + tid; i < end; i += 256)
    out[i] = expf(scores0[i] + scores1[i] - gm) * inv;
}

extern "C" void kernel_launch(void* const* d_in, const int* in_sizes, int n_in,
                              void* d_out, int out_size, void* d_ws, size_t ws_size,
                              hipStream_t stream)
{
  const float* hidden = (const float*)d_in[0];
  const float* enc    = (const float*)d_in[1];
  const int*   seg    = (const int*)d_in[2];
  const float* W      = (const float*)d_in[3];
  const float* vvec   = (const float*)d_in[4];
  float* out = (float*)d_out;

  // ws layout: scores0(512K) | scores1(512K) | hproj(128K) | w2hi(512K) | w2lo(512K)
  float* scores0 = (float*)d_ws;
  float* scores1 = scores0 + NROWS;
  float* hproj   = scores1 + NROWS;
  u16*   w2hi    = (u16*)(hproj + NSEG * HH);
  u16*   w2lo    = w2hi + (size_t)HH * HH;

  prep_kernel<<<1024 + NSEG * 4, 256, 0, stream>>>(hidden, W, hproj, w2hi, w2lo);
  gemm_fused_kernel<<<(NROWS / BM) * 2, 512, 0, stream>>>(enc, w2hi, w2lo,
                                                          hproj, vvec, seg,
                                                          scores0, scores1);
  seg_softmax_kernel<<<NSEG, 256, 0, stream>>>(scores0, scores1, seg, out);
}

// Round 9
// 657.710 us; speedup vs baseline: 2.7163x; 2.7163x over previous
//
#include <hip/hip_runtime.h>
#include <math.h>

#define NROWS 131072
#define NSEG  64
#define HH    512
#define BM    256
#define BN    128
#define BK    32
#define NT    (HH / BK)   // 16 K-steps

typedef unsigned short u16;
typedef unsigned int   u32;
typedef __attribute__((ext_vector_type(8))) short short8;
typedef __attribute__((ext_vector_type(4))) float f32x4;
typedef __attribute__((ext_vector_type(4))) u32   u32x4;

__device__ __forceinline__ u32 f2u(float f){ union {float f; u32 u;} c; c.f=f; return c.u; }
__device__ __forceinline__ float u2f(u32 u){ union {u32 u; float f;} c; c.u=u; return c.f; }
__device__ __forceinline__ u16 bf16_rne(float f){
  u32 u = f2u(f);
  u32 r = u + 0x7FFFu + ((u >> 16) & 1u);
  return (u16)(r >> 16);
}
__device__ __forceinline__ float fast_tanh(float x){
  float e = __expf(2.0f * x);
  return 1.0f - __fdividef(2.0f, e + 1.0f);
}
// async 16B global->LDS; LDS dest is wave-uniform base + lane*16
__device__ __forceinline__ void gload_lds16(const void* g, void* l) {
  __builtin_amdgcn_global_load_lds((const __attribute__((address_space(1))) void*)g,
                                   (__attribute__((address_space(3))) void*)l, 16, 0, 0);
}

// ---------------- prep: fused w2split (blocks 0..1023) + hproj (blocks 1024..1279)
__global__ __launch_bounds__(256)
void prep_kernel(const float* __restrict__ hidden, const float* __restrict__ W,
                 float* __restrict__ hproj, u16* __restrict__ w2hi, u16* __restrict__ w2lo)
{
  const int bid = blockIdx.x;
  if (bid < 1024) {
    // split W2 = W[:, 512:1024] into bf16 hi/lo, row-major [j][k]
    const int idx = bid * 256 + threadIdx.x;   // j*512 + k
    const int j = idx >> 9, k = idx & 511;
    const float x = W[(size_t)j * 1024 + 512 + k];
    const u32 u = f2u(x);
    w2hi[idx] = (u16)(u >> 16);
    w2lo[idx] = bf16_rne(x - u2f(u & 0xFFFF0000u));
  } else {
    // hproj[b][j] = sum_k hidden[b][k] * W[j][k]
    const int b    = (bid - 1024) >> 2;        // segment
    const int q    = (bid - 1024) & 3;         // j-quarter
    const int tid  = threadIdx.x;
    const int wave = tid >> 6;
    const int lane = tid & 63;
    const float* hrow = hidden + (size_t)b * HH + lane * 8;
    const float4 h0 = *(const float4*)(hrow);
    const float4 h1 = *(const float4*)(hrow + 4);
    for (int j = q * 128 + wave; j < q * 128 + 128; j += 4) {
      const float* wrow = W + (size_t)j * 1024 + lane * 8;
      const float4 w0 = *(const float4*)(wrow);
      const float4 w1 = *(const float4*)(wrow + 4);
      float acc = h0.x*w0.x + h0.y*w0.y + h0.z*w0.z + h0.w*w0.w
                + h1.x*w1.x + h1.y*w1.y + h1.z*w1.z + h1.w*w1.w;
      #pragma unroll
      for (int o = 32; o; o >>= 1) acc += __shfl_xor(acc, o);
      if (lane == 0) hproj[(size_t)b * HH + j] = acc;
    }
  }
}

// ---------------- fused GEMM v8: 256x128 block tile, 512 thr / 8 waves (4Mx2N),
// WAVE TILE 64x64 (acc[4][4] = 64 regs -> total ~120 regs, genuinely fits
// __launch_bounds__(512,4)'s 128-reg unified V+A cap with NO spill) ->
// 2 blocks/CU, 4 waves/SIMD: one block's barrier stalls are filled by the
// other block's waves. B fragments load DIRECTLY from global (w2hi/lo = 1 MB,
// L2-resident; 16 KB K-slab per block is L1-sized) -> LDS traffic is A-only
// (8 b128/wave/K-step), killing the v1-style LDS-unit wall at 16 waves/CU.
// A staged fp32 via global_load_lds (XOR-swizzled, double-buffered, counted
// vmcnt(4) T4, 2 raw barriers/K-step); A split hi/lo in-register (v_perm),
// software-pipelined one K-step ahead (SPLITA in the tail). XCD pairing: the
// 4 col-quarter blocks of a row-tile share b&7 (same XCD, <=24 dispatch slots
// apart) -> A re-reads L2-hit. 3-product split-bf16 MFMA, fused tanh+dot-v
// epilogue; per-colq score buffers, race-free LDS cross-wave reduction.
__global__ __launch_bounds__(512, 4)
void gemm_fused_kernel(const float* __restrict__ enc,
                       const u16* __restrict__ w2hi, const u16* __restrict__ w2lo,
                       const float* __restrict__ hproj, const float* __restrict__ vvec,
                       const int* __restrict__ seg, float* __restrict__ scores)
{
  __shared__ float sAf[2][BM * BK];   // 2 x 32 KB fp32 A tile
  __shared__ float spart[8][64];      // 2 KB: per-wave per-row partials

  const int tid = threadIdx.x;
  const int b   = blockIdx.x;
  // row-tile = (b>>5)*8 + (b&7) in 0..511; col-quarter = (b>>3)&3.
  // The 4 col-blocks of a row-tile are b, b+8, b+16, b+24: same b&7 -> same
  // XCD (hw round-robins blockIdx%8), temporally adjacent -> A re-read L2-hit.
  const int rt   = ((b >> 5) << 3) | (b & 7);
  const int colq = (b >> 3) & 3;
  const int row0 = rt * BM;
  const int col0 = colq * BN;

  const int wave = tid >> 6;
  const int lane = tid & 63;
  const int wrow = (wave >> 1) * 64;    // 4 row-waves
  const int wcol = (wave & 1) * 64;     // 2 col-waves
  const int l15  = lane & 15;
  const int quad = lane >> 4;

  // A staging: per issue 64 rows x 32 f32 (512 thr x 16 B). Thread t -> phys
  // chunk t&7 of row t>>3; source chunk XOR-swizzled with (row&7) so the
  // swizzled read below unswizzles (both-sides-or-neither).
  const int arow = tid >> 3;                        // 0..63
  const int acol = ((tid & 7) ^ (arow & 7)) * 4;
  const float* gA = enc + (size_t)(row0 + arow) * HH + acol;
  const int awb = wave * 256;                       // f32, wave-uniform base per issue

  // B fragment base: lane reads col (col0+wcol+l15), k-chunk quad*8.
  // j-frag adds j*16 cols = j*16*HH u16; K-step adds t*BK.
  const u16* pBh = w2hi + (size_t)(col0 + wcol + l15) * HH + quad * 8;
  const u16* pBl = w2lo + (size_t)(col0 + wcol + l15) * HH + quad * 8;

  f32x4 acc[4][4];
  #pragma unroll
  for (int i = 0; i < 4; i++)
    #pragma unroll
    for (int j = 0; j < 4; j++)
      acc[i][j] = (f32x4){0.f, 0.f, 0.f, 0.f};

  short8 ah[4], al[4];   // pre-split A fragments for the CURRENT K-step

  // 4 global_load_lds per wave per A tile
  #define STAGE(dst, kk)                                                          \
  { _Pragma("unroll") for (int i = 0; i < 4; i++)                                 \
      gload_lds16(gA + (size_t)i * 64 * HH + (kk), &sAf[dst][i * 2048 + awb]); }

  // A fragments from buffer src: read fp32, split hi/lo via v_perm
  #define SPLITA(src)                                                             \
  { _Pragma("unroll") for (int i = 0; i < 4; i++) {                               \
      const int r  = wrow + i * 16 + l15;                                         \
      const int c0 = ((2 * quad)     ^ (r & 7)) * 4;                              \
      const int c1 = ((2 * quad + 1) ^ (r & 7)) * 4;                              \
      const f32x4 x0 = *(const f32x4*)&sAf[src][r * BK + c0];                     \
      const f32x4 x1 = *(const f32x4*)&sAf[src][r * BK + c1];                     \
      union { u32x4 w; short8 s; } Hh, Ll;                                        \
      _Pragma("unroll") for (int p = 0; p < 4; p++) {                             \
        const float xa = (p < 2) ? x0[2 * p] : x1[2 * p - 4];                     \
        const float xb = (p < 2) ? x0[2 * p + 1] : x1[2 * p - 3];                 \
        const u32 ua = f2u(xa), ub = f2u(xb);                                     \
        Hh.w[p] = __builtin_amdgcn_perm(ub, ua, 0x07060302u);                     \
        const float ra = xa - u2f(ua & 0xFFFF0000u);                              \
        const float rb = xb - u2f(ub & 0xFFFF0000u);                              \
        Ll.w[p] = __builtin_amdgcn_perm(f2u(rb), f2u(ra), 0x07060302u);           \
      }                                                                           \
      ah[i] = Hh.s;                                                               \
      al[i] = Ll.s;                                                               \
    } }

  // ---- prologue: stage A tiles 0 and 1; split A(tile 0) into registers ----
  STAGE(0, 0);
  STAGE(1, BK);
  asm volatile("s_waitcnt vmcnt(4)" ::: "memory");   // tile 0 resident; tile 1 in flight
  __builtin_amdgcn_s_barrier();                      // block-wide residency of tile 0
  asm volatile("" ::: "memory");
  SPLITA(0);

  int bb = 0;
  for (int t = 0; t < NT; ++t) {
    // ---- MFMA phase: B direct from global (L1/L2-hot), 48 MFMA on pre-split A ----
    __builtin_amdgcn_s_setprio(1);
    #pragma unroll
    for (int j = 0; j < 4; j++) {
      const short8 bh = *(const short8*)(pBh + j * 16 * HH + t * BK);
      const short8 bl = *(const short8*)(pBl + j * 16 * HH + t * BK);
      #pragma unroll
      for (int i = 0; i < 4; i++) {
        acc[i][j] = __builtin_amdgcn_mfma_f32_16x16x32_bf16(ah[i], bh, acc[i][j], 0, 0, 0);
        acc[i][j] = __builtin_amdgcn_mfma_f32_16x16x32_bf16(al[i], bh, acc[i][j], 0, 0, 0);
        acc[i][j] = __builtin_amdgcn_mfma_f32_16x16x32_bf16(ah[i], bl, acc[i][j], 0, 0, 0);
      }
    }
    __builtin_amdgcn_s_setprio(0);

    // ---- barrier #1: all waves past SPLITA(t) and MFMA(t) -> sAf[bb] free ----
    asm volatile("" ::: "memory");
    __builtin_amdgcn_s_barrier();
    asm volatile("" ::: "memory");

    if (t + 2 < NT) STAGE(bb, (t + 2) * BK);         // A tile t+2 into freed buffer
    // in-order vmem retirement: <=4 outstanding => tile t+1 (and older B) retired
    if (t + 2 < NT)      { asm volatile("s_waitcnt vmcnt(4)" ::: "memory"); }
    else if (t + 1 < NT) { asm volatile("s_waitcnt vmcnt(0)" ::: "memory"); }

    // ---- barrier #2: tile t+1 resident block-wide ----
    asm volatile("" ::: "memory");
    __builtin_amdgcn_s_barrier();
    asm volatile("" ::: "memory");

    if (t + 1 < NT) SPLITA(bb ^ 1);                  // A(t+1) -> regs; overlaps next MFMA phase
    bb ^= 1;
  }
  #undef SPLITA
  #undef STAGE

  // ---- epilogue: + hproj, tanh, dot v, reduce over the wave's 64 cols,
  // deposit per-row partial in LDS, cross-wave sum of the two col-waves,
  // one coalesced store per row into this block's col-quarter buffer. ----
  int   jn[4];
  float vv[4];
  #pragma unroll
  for (int j = 0; j < 4; j++) { jn[j] = col0 + wcol + j * 16 + l15; vv[j] = vvec[jn[j]]; }

  #pragma unroll
  for (int i = 0; i < 4; i++) {
    #pragma unroll
    for (int r = 0; r < 4; r++) {
      const int lr = wrow + i * 16 + quad * 4 + r;           // local row 0..255
      const float* hp = hproj + (size_t)seg[row0 + lr] * HH;
      float p = 0.f;
      #pragma unroll
      for (int j = 0; j < 4; j++) {
        const float c = acc[i][j][r] + hp[jn[j]];
        p += fast_tanh(c) * vv[j];
      }
      p += __shfl_xor(p, 1);
      p += __shfl_xor(p, 2);
      p += __shfl_xor(p, 4);
      p += __shfl_xor(p, 8);
      if (l15 == 0) spart[wave][i * 16 + quad * 4 + r] = p;  // wave's 64-row slab
    }
  }
  __syncthreads();

  // waves 2k (cols 0..63) and 2k+1 (cols 64..127) cover the same rows:
  // sum the pair; one writer per (row, col-quarter) globally.
  float* __restrict__ sbuf = scores + (size_t)colq * NROWS;
  if (tid < 256) {
    const int rw = tid >> 6;          // row-wave 0..3
    const int rr = tid & 63;
    sbuf[row0 + tid] = spart[rw * 2][rr] + spart[rw * 2 + 1][rr];
  }
}

// ---------------- segment softmax: one block per segment (ids sorted);
// scores = sum of 4 col-quarter partial buffers
__global__ __launch_bounds__(256)
void seg_softmax_kernel(const float* __restrict__ scores, const int* __restrict__ seg,
                        float* __restrict__ out)
{
  const int b    = blockIdx.x;
  const int tid  = threadIdx.x;
  const int wv   = tid >> 6;
  const int lane = tid & 63;
  __shared__ float red[4];

  const float* s0 = scores;
  const float* s1 = scores + NROWS;
  const float* s2 = scores + 2 * (size_t)NROWS;
  const float* s3 = scores + 3 * (size_t)NROWS;

  int lo = 0, hi = NROWS;
  while (lo < hi) { int mid = (lo + hi) >> 1; if (seg[mid] < b) lo = mid + 1; else hi = mid; }
  const int start = lo;
  lo = 0; hi = NROWS;
  while (lo < hi) { int mid = (lo + hi) >> 1; if (seg[mid] < b + 1) lo = mid + 1; else hi = mid; }
  const int end = lo;

  float lm = -3.4e38f;
  for (int i = start + tid; i < end; i += 256)
    lm = fmaxf(lm, (s0[i] + s1[i]) + (s2[i] + s3[i]));
  #pragma unroll
  for (int o = 32; o; o >>= 1) lm = fmaxf(lm, __shfl_xor(lm, o));
  if (lane == 0) red[wv] = lm;
  __syncthreads();
  const float gm = fmaxf(fmaxf(red[0], red[1]), fmaxf(red[2], red[3]));
  __syncthreads();

  float ls = 0.f;
  for (int i = start + tid; i < end; i += 256)
    ls += expf((s0[i] + s1[i]) + (s2[i] + s3[i]) - gm);
  #pragma unroll
  for (int o = 32; o; o >>= 1) ls += __shfl_xor(ls, o);
  if (lane == 0) red[wv] = ls;
  __syncthreads();
  const float denom = red[0] + red[1] + red[2] + red[3];
  const float inv = 1.0f / denom;

  for (int i = start + tid; i < end; i += 256)
    out[i] = expf((s0[i] + s1[i]) + (s2[i] + s3[i]) - gm) * inv;
}

extern "C" void kernel_launch(void* const* d_in, const int* in_sizes, int n_in,
                              void* d_out, int out_size, void* d_ws, size_t ws_size,
                              hipStream_t stream)
{
  const float* hidden = (const float*)d_in[0];
  const float* enc    = (const float*)d_in[1];
  const int*   seg    = (const int*)d_in[2];
  const float* W      = (const float*)d_in[3];
  const float* vvec   = (const float*)d_in[4];
  float* out = (float*)d_out;

  // ws layout: scores(4 x 512K = 2M) | hproj(128K) | w2hi(512K) | w2lo(512K)
  float* scores = (float*)d_ws;
  float* hproj  = scores + 4 * (size_t)NROWS;
  u16*   w2hi   = (u16*)(hproj + NSEG * HH);
  u16*   w2lo   = w2hi + (size_t)HH * HH;

  prep_kernel<<<1024 + NSEG * 4, 256, 0, stream>>>(hidden, W, hproj, w2hi, w2lo);
  gemm_fused_kernel<<<(NROWS / BM) * 4, 512, 0, stream>>>(enc, w2hi, w2lo,
                                                          hproj, vvec, seg, scores);
  seg_softmax_kernel<<<NSEG, 256, 0, stream>>>(scores, seg, out);
}